// Round 12
// baseline (1165.997 us; speedup 1.0000x reference)
//
#include <hip/hip_runtime.h>
#include <hip/hip_cooperative_groups.h>

namespace cg = cooperative_groups;

#define S 256
#define D 256
#define DFF 1024
typedef unsigned int uint32;

__device__ __forceinline__ float wave_sum(float v) {
#pragma unroll
    for (int o = 32; o; o >>= 1) v += __shfl_xor(v, o, 64);
    return v;
}
__device__ __forceinline__ float wave_max(float v) {
#pragma unroll
    for (int o = 32; o; o >>= 1) v = fmaxf(v, __shfl_xor(v, o, 64));
    return v;
}
__device__ __forceinline__ uint32 bf16rne(float f) {
    uint32 u = __float_as_uint(f);
    return (u + 0x7fffu + ((u >> 16) & 1u)) >> 16;
}

struct P {
    const int* x; const float* mask; const int* use_pos; const float* pos_enc;
    const float* emb_W; const float* emb_b;
    const float* nn_W1; const float* nn_b1; const float* nn_W2; const float* nn_b2;
    const float* w_W; const float* w_b; const float* out_W; const float* out_b;
    const float* ffn_W1; const float* ffn_b1; const float* ffn_W2; const float* ffn_b2;
    const float* ln1_g; const float* ln1_b; const float* ln2_g; const float* ln2_b;
    float* h; float* qkv; float* qa; float* qbT; float* g; float* gT;
    float* attn; float* ao; float* o1; float* f1; float* pp; float* f2;
    uint32* pw; float* out;
};

// 16-way K-split reduce + store. Uses lds as [16][8][64]; defines r, cc, s for STORE.
#define REDSTORE(STORE) \
    { _Pragma("unroll") for (int r = 0; r < 8; r++) lds[(kq*8 + r)*64 + cl] = acc[r]; } \
    __syncthreads(); \
    if (tid < 512) { \
        int r = tid >> 6, cc = tid & 63; \
        float s = 0.f; \
        _Pragma("unroll") for (int q = 0; q < 16; q++) s += lds[(q*8 + r)*64 + cc]; \
        STORE; \
    } \
    __syncthreads();

__global__ __launch_bounds__(1024) void k_all(P p)
{
    cg::grid_group grid = cg::this_grid();
    __shared__ float lds[8192];           // 32 KB
    const int tid = threadIdx.x;
    const int bid = blockIdx.x;           // 0..255
    const int kq = tid >> 6, cl = tid & 63;
    const int bx = bid >> 2, by = bid & 3;
    const int r0 = bx * 8;                // GEMM row block

    // ---------- weight convert: pack to bf16 row-pairs (grid-stride) ----------
    for (int i = bid * 1024 + tid; i < 720896; i += 262144) {
        const float* src; int local, c, N;
        if (i < 65536)       { src = p.w_W;    local = i;          c = local & 255;  N = 256; }
        else if (i < 131072) { src = p.nn_W1;  local = i - 65536;  c = local & 255;  N = 256; }
        else if (i < 196608) { src = p.out_W;  local = i - 131072; c = local & 255;  N = 256; }
        else if (i < 458752) { src = p.ffn_W1; local = i - 196608; c = local & 1023; N = 1024; }
        else                 { src = p.ffn_W2; local = i - 458752; c = local & 255;  N = 256; }
        float a0 = src[2 * local - c];
        float a1 = src[2 * local - c + N];
        p.pw[i] = (bf16rne(a1) << 16) | bf16rne(a0);
    }

    // ---------- embed + positional enc: rows bid*2, bid*2+1 (tid<512) ----------
    {
        int g2 = tid >> 8, c = tid & 255;
        int r = bid * 2 + g2;
        float mv = 0.f;
        if (tid < 512) {
            int b = r >> 8, sq = r & 255;
            mv = (c <= sq) ? (1.0f - p.mask[b * S + c]) : 0.f;
        }
        if (tid < 512) {
            float w = wave_sum(mv);
            if (!(tid & 63)) lds[tid >> 6] = w;
        }
        __syncthreads();
        if (tid < 512) {
            float cum = lds[g2*4] + lds[g2*4+1] + lds[g2*4+2] + lds[g2*4+3];
            int idx = (int)(cum + 0.5f);
            int xv = p.x[r];
            float acc = p.emb_b[c];
#pragma unroll
            for (int k = 0; k < 16; k++)
                if ((xv >> k) & 1) acc += p.emb_W[k * D + c];
            acc *= 16.0f;
            if (p.use_pos[0]) acc += p.pos_enc[idx * D + c];
            p.h[r * D + c] = acc;
        }
        __syncthreads();
    }
    grid.sync();

    for (int l = 0; l < 2; l++) {
        // ---------- qkv = h @ wW + wb ----------
        {
            const uint32* Wp = p.pw + l * 32768;
            int c = by * 64 + cl, k0 = kq * 16;
            float acc[8] = {0.f,0.f,0.f,0.f,0.f,0.f,0.f,0.f};
#pragma unroll
            for (int kk = 0; kk < 16; kk += 4) {
                int k = k0 + kk;
                uint32 wpA = Wp[(k >> 1) * D + c];
                uint32 wpB = Wp[((k >> 1) + 1) * D + c];
                float w0 = __uint_as_float(wpA << 16), w1 = __uint_as_float(wpA & 0xffff0000u);
                float w2v = __uint_as_float(wpB << 16), w3 = __uint_as_float(wpB & 0xffff0000u);
#pragma unroll
                for (int r = 0; r < 8; r++) {
                    float4 hv = *(const float4*)&p.h[(r0 + r) * D + k];
                    acc[r] = fmaf(hv.x, w0, acc[r]); acc[r] = fmaf(hv.y, w1, acc[r]);
                    acc[r] = fmaf(hv.z, w2v, acc[r]); acc[r] = fmaf(hv.w, w3, acc[r]);
                }
            }
            REDSTORE(p.qkv[(r0 + r) * D + by*64 + cc] = s + p.w_b[l * D + by*64 + cc])
        }
        grid.sync();

        // ---------- qa = qkv@W1a + b1 ; qbT = (qkv@W1b)^T  (2 passes) ----------
        for (int half = 0; half < 2; half++) {
            const uint32* Wp = p.pw + 65536 + half * 32768;
            int c0 = by * 64;
            int c = c0 + cl, k0 = kq * 16;
            float acc[8] = {0.f,0.f,0.f,0.f,0.f,0.f,0.f,0.f};
#pragma unroll
            for (int kk = 0; kk < 16; kk += 4) {
                int k = k0 + kk;
                uint32 wpA = Wp[(k >> 1) * D + c];
                uint32 wpB = Wp[((k >> 1) + 1) * D + c];
                float w0 = __uint_as_float(wpA << 16), w1 = __uint_as_float(wpA & 0xffff0000u);
                float w2v = __uint_as_float(wpB << 16), w3 = __uint_as_float(wpB & 0xffff0000u);
#pragma unroll
                for (int r = 0; r < 8; r++) {
                    float4 hv = *(const float4*)&p.qkv[(r0 + r) * D + k];
                    acc[r] = fmaf(hv.x, w0, acc[r]); acc[r] = fmaf(hv.y, w1, acc[r]);
                    acc[r] = fmaf(hv.z, w2v, acc[r]); acc[r] = fmaf(hv.w, w3, acc[r]);
                }
            }
            if (half == 0) {
                REDSTORE(p.qa[(r0 + r) * D + c0 + cc] = s + p.nn_b1[c0 + cc])
            } else {
                REDSTORE({ int row = r0 + r; int b = row >> 8;
                           p.qbT[b * (S * D) + (c0 + cc) * S + (row & 255)] = s; })
            }
        }
        grid.sync();

        // ---------- g[b,i,j] = sum_h relu(qa[i,h]+qb[j,h])*w2[h]  (+ gT) ----------
        {
            int b = r0 >> 8;
            int j0 = by * 64;
            const float* qbTb = p.qbT + b * (S * D);
            int k0 = kq * 16;
            float acc[8] = {0.f,0.f,0.f,0.f,0.f,0.f,0.f,0.f};
#pragma unroll
            for (int hh = 0; hh < 16; hh += 4) {
                int hgl = k0 + hh;
                float4 wv = *(const float4*)&p.nn_W2[hgl];
                float b0 = qbTb[(hgl + 0) * S + j0 + cl];
                float b1 = qbTb[(hgl + 1) * S + j0 + cl];
                float b2 = qbTb[(hgl + 2) * S + j0 + cl];
                float b3 = qbTb[(hgl + 3) * S + j0 + cl];
#pragma unroll
                for (int r = 0; r < 8; r++) {
                    float4 qv = *(const float4*)&p.qa[(r0 + r) * D + hgl];
                    acc[r] = fmaf(fmaxf(qv.x + b0, 0.f), wv.x, acc[r]);
                    acc[r] = fmaf(fmaxf(qv.y + b1, 0.f), wv.y, acc[r]);
                    acc[r] = fmaf(fmaxf(qv.z + b2, 0.f), wv.z, acc[r]);
                    acc[r] = fmaf(fmaxf(qv.w + b3, 0.f), wv.w, acc[r]);
                }
            }
            REDSTORE({ p.g[(r0 + r) * S + j0 + cc] = s;
                       p.gT[(b * S + j0 + cc) * S + ((r0 + r) & 255)] = s; })
        }
        grid.sync();

        // ---------- softmax rows bid*2, bid*2+1 (tid<512) ----------
        {
            int g2 = tid >> 8, t = tid & 255;
            int i = bid * 2 + g2;
            float sv = 0.f;
            if (tid < 512) {
                int b = i >> 8;
                sv = p.g[i * S + t] + p.gT[i * S + t] + 2.0f * p.nn_b2[0]
                   + p.mask[b * S + t] * (-1e9f);
                float wm = wave_max(sv);
                if (!(tid & 63)) lds[tid >> 6] = wm;
            }
            __syncthreads();
            float m = fmaxf(fmaxf(lds[g2*4], lds[g2*4+1]), fmaxf(lds[g2*4+2], lds[g2*4+3]));
            float e = (tid < 512) ? __expf(sv - m) : 0.f;
            __syncthreads();
            if (tid < 512) {
                float ws2 = wave_sum(e);
                if (!(tid & 63)) lds[tid >> 6] = ws2;
            }
            __syncthreads();
            if (tid < 512) {
                float inv = 1.0f / (lds[g2*4] + lds[g2*4+1] + lds[g2*4+2] + lds[g2*4+3]);
                p.attn[i * S + t] = e * inv;
            }
            __syncthreads();
        }
        grid.sync();

        // ---------- ao = attn @ qkv (f32 V) ----------
        {
            int b = r0 >> 8;
            const float* W = p.qkv + b * (S * D);
            int c = by * 64 + cl, k0 = kq * 16;
            float acc[8] = {0.f,0.f,0.f,0.f,0.f,0.f,0.f,0.f};
#pragma unroll
            for (int kk = 0; kk < 16; kk += 4) {
                int k = k0 + kk;
                float w0 = W[(k + 0) * D + c], w1 = W[(k + 1) * D + c];
                float w2v = W[(k + 2) * D + c], w3 = W[(k + 3) * D + c];
#pragma unroll
                for (int r = 0; r < 8; r++) {
                    float4 av = *(const float4*)&p.attn[(r0 + r) * S + k];
                    acc[r] = fmaf(av.x, w0, acc[r]); acc[r] = fmaf(av.y, w1, acc[r]);
                    acc[r] = fmaf(av.z, w2v, acc[r]); acc[r] = fmaf(av.w, w3, acc[r]);
                }
            }
            REDSTORE(p.ao[(r0 + r) * D + by*64 + cc] = s)
        }
        grid.sync();

        // ---------- pp = ao @ outW ----------
        {
            const uint32* Wp = p.pw + 131072 + l * 32768;
            int c = by * 64 + cl, k0 = kq * 16;
            float acc[8] = {0.f,0.f,0.f,0.f,0.f,0.f,0.f,0.f};
#pragma unroll
            for (int kk = 0; kk < 16; kk += 4) {
                int k = k0 + kk;
                uint32 wpA = Wp[(k >> 1) * D + c];
                uint32 wpB = Wp[((k >> 1) + 1) * D + c];
                float w0 = __uint_as_float(wpA << 16), w1 = __uint_as_float(wpA & 0xffff0000u);
                float w2v = __uint_as_float(wpB << 16), w3 = __uint_as_float(wpB & 0xffff0000u);
#pragma unroll
                for (int r = 0; r < 8; r++) {
                    float4 hv = *(const float4*)&p.ao[(r0 + r) * D + k];
                    acc[r] = fmaf(hv.x, w0, acc[r]); acc[r] = fmaf(hv.y, w1, acc[r]);
                    acc[r] = fmaf(hv.z, w2v, acc[r]); acc[r] = fmaf(hv.w, w3, acc[r]);
                }
            }
            REDSTORE(p.pp[(r0 + r) * D + by*64 + cc] = s)
        }
        grid.sync();

        // ---------- o1 = LN1(h + pp + outb): rows bid*2, bid*2+1 ----------
        {
            int g2 = tid >> 8, c = tid & 255;
            int r = bid * 2 + g2;
            float v = 0.f;
            if (tid < 512) {
                v = p.h[r * D + c] + p.pp[r * D + c] + p.out_b[l * D + c];
                float s1 = wave_sum(v);
                if (!(tid & 63)) lds[tid >> 6] = s1;
            }
            __syncthreads();
            float mu = (lds[g2*4] + lds[g2*4+1] + lds[g2*4+2] + lds[g2*4+3]) * (1.0f/256.0f);
            float dv = v - mu;
            __syncthreads();
            if (tid < 512) {
                float s2 = wave_sum(dv * dv);
                if (!(tid & 63)) lds[tid >> 6] = s2;
            }
            __syncthreads();
            if (tid < 512) {
                float var = (lds[g2*4] + lds[g2*4+1] + lds[g2*4+2] + lds[g2*4+3]) * (1.0f/256.0f);
                p.o1[r * D + c] = dv * rsqrtf(var + 1e-6f) * p.ln1_g[l*D + c] + p.ln1_b[l*D + c];
            }
            __syncthreads();
        }
        grid.sync();

        // ---------- f1 = relu(o1 @ ffnW1 + b1)  (4 col-tiles/block) ----------
        for (int it = 0; it < 4; it++) {
            const uint32* Wp = p.pw + 196608 + l * 131072;
            int c0 = (by * 4 + it) * 64;
            int c = c0 + cl, k0 = kq * 16;
            float acc[8] = {0.f,0.f,0.f,0.f,0.f,0.f,0.f,0.f};
#pragma unroll
            for (int kk = 0; kk < 16; kk += 4) {
                int k = k0 + kk;
                uint32 wpA = Wp[(k >> 1) * DFF + c];
                uint32 wpB = Wp[((k >> 1) + 1) * DFF + c];
                float w0 = __uint_as_float(wpA << 16), w1 = __uint_as_float(wpA & 0xffff0000u);
                float w2v = __uint_as_float(wpB << 16), w3 = __uint_as_float(wpB & 0xffff0000u);
#pragma unroll
                for (int r = 0; r < 8; r++) {
                    float4 hv = *(const float4*)&p.o1[(r0 + r) * D + k];
                    acc[r] = fmaf(hv.x, w0, acc[r]); acc[r] = fmaf(hv.y, w1, acc[r]);
                    acc[r] = fmaf(hv.z, w2v, acc[r]); acc[r] = fmaf(hv.w, w3, acc[r]);
                }
            }
            REDSTORE(p.f1[(r0 + r) * DFF + c0 + cc] = fmaxf(s + p.ffn_b1[l*DFF + c0 + cc], 0.f))
        }
        grid.sync();

        // ---------- f2 = f1 @ ffnW2  (K=1024, chunk 64) ----------
        {
            const uint32* Wp = p.pw + 458752 + l * 131072;
            int c = by * 64 + cl, k0 = kq * 64;
            float acc[8] = {0.f,0.f,0.f,0.f,0.f,0.f,0.f,0.f};
#pragma unroll 4
            for (int kk = 0; kk < 64; kk += 4) {
                int k = k0 + kk;
                uint32 wpA = Wp[(k >> 1) * D + c];
                uint32 wpB = Wp[((k >> 1) + 1) * D + c];
                float w0 = __uint_as_float(wpA << 16), w1 = __uint_as_float(wpA & 0xffff0000u);
                float w2v = __uint_as_float(wpB << 16), w3 = __uint_as_float(wpB & 0xffff0000u);
#pragma unroll
                for (int r = 0; r < 8; r++) {
                    float4 hv = *(const float4*)&p.f1[(r0 + r) * DFF + k];
                    acc[r] = fmaf(hv.x, w0, acc[r]); acc[r] = fmaf(hv.y, w1, acc[r]);
                    acc[r] = fmaf(hv.z, w2v, acc[r]); acc[r] = fmaf(hv.w, w3, acc[r]);
                }
            }
            REDSTORE(p.f2[(r0 + r) * D + by*64 + cc] = s)
        }
        grid.sync();

        // ---------- h' = LN2(o1 + f2 + b2): rows bid*2, bid*2+1 ----------
        {
            float* hout = (l == 1) ? p.out : p.h;
            int g2 = tid >> 8, c = tid & 255;
            int r = bid * 2 + g2;
            float v = 0.f;
            if (tid < 512) {
                v = p.o1[r * D + c] + p.f2[r * D + c] + p.ffn_b2[l * D + c];
                float s1 = wave_sum(v);
                if (!(tid & 63)) lds[tid >> 6] = s1;
            }
            __syncthreads();
            float mu = (lds[g2*4] + lds[g2*4+1] + lds[g2*4+2] + lds[g2*4+3]) * (1.0f/256.0f);
            float dv = v - mu;
            __syncthreads();
            if (tid < 512) {
                float s2 = wave_sum(dv * dv);
                if (!(tid & 63)) lds[tid >> 6] = s2;
            }
            __syncthreads();
            if (tid < 512) {
                float var = (lds[g2*4] + lds[g2*4+1] + lds[g2*4+2] + lds[g2*4+3]) * (1.0f/256.0f);
                hout[r * D + c] = dv * rsqrtf(var + 1e-6f) * p.ln2_g[l*D + c] + p.ln2_b[l*D + c];
            }
            __syncthreads();
        }
        grid.sync();
    }
}

extern "C" void kernel_launch(void* const* d_in, const int* in_sizes, int n_in,
                              void* d_out, int out_size, void* d_ws, size_t ws_size,
                              hipStream_t stream)
{
    P p;
    p.x       = (const int*)d_in[0];
    p.mask    = (const float*)d_in[1];
    p.use_pos = (const int*)d_in[3];
    p.pos_enc = (const float*)d_in[4];
    p.emb_W   = (const float*)d_in[5];
    p.emb_b   = (const float*)d_in[6];
    p.nn_W1   = (const float*)d_in[7];
    p.nn_b1   = (const float*)d_in[8];
    p.nn_W2   = (const float*)d_in[9];
    p.nn_b2   = (const float*)d_in[10];
    p.w_W     = (const float*)d_in[11];
    p.w_b     = (const float*)d_in[12];
    p.out_W   = (const float*)d_in[13];
    p.out_b   = (const float*)d_in[14];
    p.ffn_W1  = (const float*)d_in[15];
    p.ffn_b1  = (const float*)d_in[16];
    p.ffn_W2  = (const float*)d_in[17];
    p.ffn_b2  = (const float*)d_in[18];
    p.ln1_g   = (const float*)d_in[19];
    p.ln1_b   = (const float*)d_in[20];
    p.ln2_g   = (const float*)d_in[21];
    p.ln2_b   = (const float*)d_in[22];

    float* ws = (float*)d_ws;
    p.h    = ws;
    p.qkv  = ws + 131072;
    p.qa   = ws + 262144;
    p.qbT  = ws + 393216;
    p.g    = ws + 524288;
    p.gT   = ws + 655360;
    p.attn = ws + 786432;
    p.ao   = ws + 917504;
    p.o1   = ws + 1048576;
    p.f1   = ws + 1179648;           // 524288
    p.pp   = ws + 1703936;           // 131072
    p.f2   = ws + 1835008;           // 131072
    p.pw   = (uint32*)(ws + 1966080);// 720896 dwords
    p.out  = (float*)d_out;

    void* args[] = { &p };
    hipLaunchCooperativeKernel((void*)k_all, dim3(256), dim3(1024), args, 0, stream);
}

// Round 14
// 198.618 us; speedup vs baseline: 5.8706x; 5.8706x over previous
//
#include <hip/hip_runtime.h>

#define S 256
#define D 256
#define DFF 1024
typedef unsigned int uint32;

__device__ __forceinline__ float wave_sum(float v) {
#pragma unroll
    for (int o = 32; o; o >>= 1) v += __shfl_xor(v, o, 64);
    return v;
}
__device__ __forceinline__ float wave_max(float v) {
#pragma unroll
    for (int o = 32; o; o >>= 1) v = fmaxf(v, __shfl_xor(v, o, 64));
    return v;
}
__device__ __forceinline__ uint32 bf16rne(float f) {
    uint32 u = __float_as_uint(f);
    return (u + 0x7fffu + ((u >> 16) & 1u)) >> 16;
}
#define DECODE(wp, w_lo, w_hi) \
    float w_lo = __uint_as_float((wp) << 16); \
    float w_hi = __uint_as_float((wp) & 0xffff0000u);

// ---------- K0: blocks 0..511 embed one row each; blocks 512..1023 cvt (grid-stride) ----------
__global__ __launch_bounds__(256) void k0(
    const int* __restrict__ x, const float* __restrict__ mask,
    const int* __restrict__ use_pos, const float* __restrict__ pos_enc,
    const float* __restrict__ emb_W, const float* __restrict__ emb_b,
    const float* __restrict__ wW, const float* __restrict__ nn,
    const float* __restrict__ ow, const float* __restrict__ f1w,
    const float* __restrict__ f2w,
    float* __restrict__ h, uint32* __restrict__ pw)
{
    int bid = blockIdx.x, tid = threadIdx.x;
    if (bid < 512) {
        __shared__ float red[4];
        int r = bid, d = tid;
        int b = r >> 8, sq = r & 255;
        float mv = (d <= sq) ? (1.0f - mask[b * S + d]) : 0.0f;
        float w = wave_sum(mv);
        if (!(tid & 63)) red[tid >> 6] = w;
        __syncthreads();
        float cum = red[0] + red[1] + red[2] + red[3];
        int idx = (int)(cum + 0.5f);
        int xv = x[r];
        float acc = emb_b[d];
#pragma unroll
        for (int k = 0; k < 16; k++)
            if ((xv >> k) & 1) acc += emb_W[k * D + d];
        acc *= 16.0f;
        if (use_pos[0]) acc += pos_enc[idx * D + d];
        h[r * D + d] = acc;
    } else {
        for (int i = (bid - 512) * 256 + tid; i < 720896; i += 131072) {
            const float* src; int local, c, N;
            if (i < 65536)       { src = wW;  local = i;          c = local & 255;  N = 256; }
            else if (i < 131072) { src = nn;  local = i - 65536;  c = local & 255;  N = 256; }
            else if (i < 196608) { src = ow;  local = i - 131072; c = local & 255;  N = 256; }
            else if (i < 458752) { src = f1w; local = i - 196608; c = local & 1023; N = 1024; }
            else                 { src = f2w; local = i - 458752; c = local & 255;  N = 256; }
            float a0 = src[2 * local - c];
            float a1 = src[2 * local - c + N];
            pw[i] = (bf16rne(a1) << 16) | bf16rne(a0);
        }
    }
}

// ---------- KA: qkv rows -> (qa rows, qbT) fused; 2 rows/block, grid 256 x 1024 ----------
__global__ __launch_bounds__(1024) void kA(
    const float* __restrict__ h, const uint32* __restrict__ Wq,
    const uint32* __restrict__ WA, const uint32* __restrict__ WB,
    const float* __restrict__ wb, const float* __restrict__ nnb1,
    float* __restrict__ qkv, float* __restrict__ qa, float* __restrict__ qbT)
{
    __shared__ float red[4][4][256];   // 16 KB
    __shared__ float qs[2][256];
    int tid = threadIdx.x;
    int i0 = blockIdx.x * 2;
    int kq = tid >> 8, c = tid & 255;
    int k0 = kq * 64;
    float a0 = 0.f, a1 = 0.f;
#pragma unroll 4
    for (int kk = 0; kk < 64; kk += 4) {
        int k = k0 + kk;
        uint32 wpA = Wq[(k >> 1) * D + c];
        uint32 wpB = Wq[((k >> 1) + 1) * D + c];
        DECODE(wpA, w0, w1); DECODE(wpB, w2v, w3);
        float4 h0 = *(const float4*)&h[i0 * D + k];
        float4 h1 = *(const float4*)&h[(i0 + 1) * D + k];
        a0 = fmaf(h0.x, w0, a0); a0 = fmaf(h0.y, w1, a0);
        a0 = fmaf(h0.z, w2v, a0); a0 = fmaf(h0.w, w3, a0);
        a1 = fmaf(h1.x, w0, a1); a1 = fmaf(h1.y, w1, a1);
        a1 = fmaf(h1.z, w2v, a1); a1 = fmaf(h1.w, w3, a1);
    }
    red[kq][0][c] = a0; red[kq][1][c] = a1;
    __syncthreads();
    if (tid < 512) {
        int r = tid >> 8, cc = tid & 255;
        float s = red[0][r][cc] + red[1][r][cc] + red[2][r][cc] + red[3][r][cc] + wb[cc];
        qkv[(i0 + r) * D + cc] = s;
        qs[r][cc] = s;
    }
    __syncthreads();
    float qa0 = 0.f, qa1 = 0.f, qb0 = 0.f, qb1 = 0.f;
#pragma unroll 4
    for (int kk = 0; kk < 64; kk += 4) {
        int k = k0 + kk;
        uint32 aA = WA[(k >> 1) * D + c], aB = WA[((k >> 1) + 1) * D + c];
        uint32 bA = WB[(k >> 1) * D + c], bB = WB[((k >> 1) + 1) * D + c];
        DECODE(aA, wa0, wa1); DECODE(aB, wa2, wa3);
        DECODE(bA, wb0, wb1); DECODE(bB, wb2, wb3);
        float q00 = qs[0][k], q01 = qs[0][k+1], q02 = qs[0][k+2], q03 = qs[0][k+3];
        float q10 = qs[1][k], q11 = qs[1][k+1], q12 = qs[1][k+2], q13 = qs[1][k+3];
        qa0 = fmaf(q00, wa0, qa0); qa0 = fmaf(q01, wa1, qa0);
        qa0 = fmaf(q02, wa2, qa0); qa0 = fmaf(q03, wa3, qa0);
        qa1 = fmaf(q10, wa0, qa1); qa1 = fmaf(q11, wa1, qa1);
        qa1 = fmaf(q12, wa2, qa1); qa1 = fmaf(q13, wa3, qa1);
        qb0 = fmaf(q00, wb0, qb0); qb0 = fmaf(q01, wb1, qb0);
        qb0 = fmaf(q02, wb2, qb0); qb0 = fmaf(q03, wb3, qb0);
        qb1 = fmaf(q10, wb0, qb1); qb1 = fmaf(q11, wb1, qb1);
        qb1 = fmaf(q12, wb2, qb1); qb1 = fmaf(q13, wb3, qb1);
    }
    __syncthreads();
    red[kq][0][c] = qa0; red[kq][1][c] = qa1; red[kq][2][c] = qb0; red[kq][3][c] = qb1;
    __syncthreads();
    {
        int idx = tid >> 8;            // 0..3: (mat = idx>>1, r = idx&1)
        int cc = tid & 255;
        float s = red[0][idx][cc] + red[1][idx][cc] + red[2][idx][cc] + red[3][idx][cc];
        int r = idx & 1, m = idx >> 1;
        int row = i0 + r;
        if (!m) qa[row * D + cc] = s + nnb1[cc];
        else {
            int b = row >> 8;
            qbT[b * (S * D) + cc * S + (row & 255)] = s;
        }
    }
}

// ---------- KB: g + gT (round-8 shape: grid (64,4) x 1024, 16-way K-split) ----------
__global__ __launch_bounds__(1024) void kB(
    const float* __restrict__ qa, const float* __restrict__ qbT,
    const float* __restrict__ w2, float* __restrict__ g, float* __restrict__ gT)
{
    __shared__ float red[16][8][64];   // 32 KB
    int ri0 = blockIdx.x * 8;
    int b = ri0 >> 8;
    int j0 = blockIdx.y * 64;
    int tid = threadIdx.x;
    int kq = tid >> 6, cl = tid & 63;
    int k0 = kq * 16;
    const float* qbTb = qbT + b * (S * D);
    float acc[8] = {0.f,0.f,0.f,0.f,0.f,0.f,0.f,0.f};
#pragma unroll
    for (int hh = 0; hh < 16; hh += 4) {
        int hgl = k0 + hh;
        float4 wv = *(const float4*)&w2[hgl];
        float b0 = qbTb[(hgl + 0) * S + j0 + cl];
        float b1 = qbTb[(hgl + 1) * S + j0 + cl];
        float b2 = qbTb[(hgl + 2) * S + j0 + cl];
        float b3 = qbTb[(hgl + 3) * S + j0 + cl];
#pragma unroll
        for (int r = 0; r < 8; r++) {
            float4 qv = *(const float4*)&qa[(ri0 + r) * D + hgl];
            acc[r] = fmaf(fmaxf(qv.x + b0, 0.f), wv.x, acc[r]);
            acc[r] = fmaf(fmaxf(qv.y + b1, 0.f), wv.y, acc[r]);
            acc[r] = fmaf(fmaxf(qv.z + b2, 0.f), wv.z, acc[r]);
            acc[r] = fmaf(fmaxf(qv.w + b3, 0.f), wv.w, acc[r]);
        }
    }
#pragma unroll
    for (int r = 0; r < 8; r++) red[kq][r][cl] = acc[r];
    __syncthreads();
    if (tid < 512) {
        int r = tid >> 6, cc = tid & 63;
        float s = 0.f;
#pragma unroll
        for (int q = 0; q < 16; q++) s += red[q][r][cc];
        g[(ri0 + r) * S + j0 + cc] = s;
        gT[(b * S + j0 + cc) * S + ((ri0 + r) & 255)] = s;
    }
}

// ---------- KC: softmax -> attn@V -> proj -> LN1; 2 rows/block, grid 256 x 1024 ----------
__global__ __launch_bounds__(1024) void kC(
    const float* __restrict__ g, const float* __restrict__ gT,
    const float* __restrict__ mask, const float* __restrict__ b2p,
    const float* __restrict__ qkv, const uint32* __restrict__ Wo,
    const float* __restrict__ outb, const float* __restrict__ h,
    const float* __restrict__ lng, const float* __restrict__ lnb,
    float* __restrict__ o1)
{
    __shared__ float red[4][2][256];   // 8 KB
    __shared__ float attn_s[2][256];
    __shared__ float ao_s[2][256];
    __shared__ float rwm[8], rws[8];
    int tid = threadIdx.x;
    int i0 = blockIdx.x * 2;
    int b = i0 >> 8;
    int g2 = tid >> 8, t = tid & 255;

    // softmax (tid < 512: 2 rows x 256)
    float sv = 0.f;
    if (tid < 512) {
        int i = i0 + g2;
        sv = g[i * S + t] + gT[i * S + t] + 2.0f * b2p[0] + mask[b * S + t] * (-1e9f);
        float wm = wave_max(sv);
        if (!(tid & 63)) rwm[tid >> 6] = wm;
    }
    __syncthreads();
    float e = 0.f;
    if (tid < 512) {
        float m = fmaxf(fmaxf(rwm[g2*4], rwm[g2*4+1]), fmaxf(rwm[g2*4+2], rwm[g2*4+3]));
        e = __expf(sv - m);
        float ws = wave_sum(e);
        if (!(tid & 63)) rws[tid >> 6] = ws;
    }
    __syncthreads();
    if (tid < 512) {
        float inv = 1.0f / (rws[g2*4] + rws[g2*4+1] + rws[g2*4+2] + rws[g2*4+3]);
        attn_s[g2][t] = e * inv;
    }
    __syncthreads();

    // av: ao = attn @ qkv (4-way j-split)
    int kq = tid >> 8, c = tid & 255;
    int j0 = kq * 64;
    const float* Qb = qkv + b * (S * D);
    float a0 = 0.f, a1 = 0.f;
#pragma unroll 4
    for (int jj = 0; jj < 64; jj += 4) {
        int j = j0 + jj;
        float w0 = Qb[(j + 0) * D + c], w1 = Qb[(j + 1) * D + c];
        float w2v = Qb[(j + 2) * D + c], w3 = Qb[(j + 3) * D + c];
        a0 = fmaf(attn_s[0][j], w0, a0);   a0 = fmaf(attn_s[0][j+1], w1, a0);
        a0 = fmaf(attn_s[0][j+2], w2v, a0); a0 = fmaf(attn_s[0][j+3], w3, a0);
        a1 = fmaf(attn_s[1][j], w0, a1);   a1 = fmaf(attn_s[1][j+1], w1, a1);
        a1 = fmaf(attn_s[1][j+2], w2v, a1); a1 = fmaf(attn_s[1][j+3], w3, a1);
    }
    red[kq][0][c] = a0; red[kq][1][c] = a1;
    __syncthreads();
    if (tid < 512) {
        int r = tid >> 8, cc = tid & 255;
        ao_s[r][cc] = red[0][r][cc] + red[1][r][cc] + red[2][r][cc] + red[3][r][cc];
    }
    __syncthreads();

    // proj: pp = ao @ outW (bf16 packed)
    int k0 = kq * 64;
    float p0 = 0.f, p1 = 0.f;
#pragma unroll 4
    for (int kk = 0; kk < 64; kk += 4) {
        int k = k0 + kk;
        uint32 wpA = Wo[(k >> 1) * D + c];
        uint32 wpB = Wo[((k >> 1) + 1) * D + c];
        DECODE(wpA, w0, w1); DECODE(wpB, w2v, w3);
        p0 = fmaf(ao_s[0][k], w0, p0);   p0 = fmaf(ao_s[0][k+1], w1, p0);
        p0 = fmaf(ao_s[0][k+2], w2v, p0); p0 = fmaf(ao_s[0][k+3], w3, p0);
        p1 = fmaf(ao_s[1][k], w0, p1);   p1 = fmaf(ao_s[1][k+1], w1, p1);
        p1 = fmaf(ao_s[1][k+2], w2v, p1); p1 = fmaf(ao_s[1][k+3], w3, p1);
    }
    __syncthreads();
    red[kq][0][c] = p0; red[kq][1][c] = p1;
    __syncthreads();

    // LN1
    float v = 0.f;
    int r = tid >> 8, cc = tid & 255;
    if (tid < 512) {
        float pp = red[0][r][cc] + red[1][r][cc] + red[2][r][cc] + red[3][r][cc] + outb[cc];
        v = h[(i0 + r) * D + cc] + pp;
        float s1 = wave_sum(v);
        if (!(tid & 63)) rwm[tid >> 6] = s1;
    }
    __syncthreads();
    float dv = 0.f;
    if (tid < 512) {
        float mu = (rwm[r*4] + rwm[r*4+1] + rwm[r*4+2] + rwm[r*4+3]) * (1.0f/256.0f);
        dv = v - mu;
        float s2 = wave_sum(dv * dv);
        if (!(tid & 63)) rws[tid >> 6] = s2;
    }
    __syncthreads();
    if (tid < 512) {
        float var = (rws[r*4] + rws[r*4+1] + rws[r*4+2] + rws[r*4+3]) * (1.0f/256.0f);
        o1[(i0 + r) * D + cc] = dv * rsqrtf(var + 1e-6f) * lng[cc] + lnb[cc];
    }
}

// ---------- KD: ffn1 -> ffn2 -> LN2; 2 rows/block, grid 256 x 1024; f1 in LDS only ----------
__global__ __launch_bounds__(1024) void kD(
    const float* __restrict__ o1, const uint32* __restrict__ W1,
    const uint32* __restrict__ W2, const float* __restrict__ b1,
    const float* __restrict__ b2, const float* __restrict__ lng,
    const float* __restrict__ lnb, float* __restrict__ hout)
{
    __shared__ float o1s[512];
    __shared__ float f1s[2][1024];     // 8 KB
    __shared__ float red[4][2][256];   // 8 KB
    __shared__ float rwm[8], rws[8];
    int tid = threadIdx.x;
    int i0 = blockIdx.x * 2;
    if (tid < 512) o1s[tid] = o1[i0 * D + tid];
    __syncthreads();

    // f1: each thread one col (0..1023), 2 rows
    float a0 = 0.f, a1 = 0.f;
#pragma unroll 4
    for (int k = 0; k < 256; k += 4) {
        uint32 wpA = W1[(k >> 1) * DFF + tid];
        uint32 wpB = W1[((k >> 1) + 1) * DFF + tid];
        DECODE(wpA, w0, w1); DECODE(wpB, w2v, w3);
        a0 = fmaf(o1s[k], w0, a0);       a0 = fmaf(o1s[k+1], w1, a0);
        a0 = fmaf(o1s[k+2], w2v, a0);    a0 = fmaf(o1s[k+3], w3, a0);
        a1 = fmaf(o1s[256+k], w0, a1);   a1 = fmaf(o1s[256+k+1], w1, a1);
        a1 = fmaf(o1s[256+k+2], w2v, a1); a1 = fmaf(o1s[256+k+3], w3, a1);
    }
    float bv = b1[tid];
    f1s[0][tid] = fmaxf(a0 + bv, 0.f);
    f1s[1][tid] = fmaxf(a1 + bv, 0.f);
    __syncthreads();

    // f2: 4-way K-split over 1024
    int kq = tid >> 8, c = tid & 255;
    int k0 = kq * 256;
    float c0 = 0.f, c1 = 0.f;
#pragma unroll 4
    for (int kk = 0; kk < 256; kk += 4) {
        int k = k0 + kk;
        uint32 wpA = W2[(k >> 1) * D + c];
        uint32 wpB = W2[((k >> 1) + 1) * D + c];
        DECODE(wpA, w0, w1); DECODE(wpB, w2v, w3);
        c0 = fmaf(f1s[0][k], w0, c0);    c0 = fmaf(f1s[0][k+1], w1, c0);
        c0 = fmaf(f1s[0][k+2], w2v, c0); c0 = fmaf(f1s[0][k+3], w3, c0);
        c1 = fmaf(f1s[1][k], w0, c1);    c1 = fmaf(f1s[1][k+1], w1, c1);
        c1 = fmaf(f1s[1][k+2], w2v, c1); c1 = fmaf(f1s[1][k+3], w3, c1);
    }
    red[kq][0][c] = c0; red[kq][1][c] = c1;
    __syncthreads();

    // LN2
    float v = 0.f;
    int r = tid >> 8, cc = tid & 255;
    if (tid < 512) {
        float f2v = red[0][r][cc] + red[1][r][cc] + red[2][r][cc] + red[3][r][cc] + b2[cc];
        v = o1s[r * 256 + cc] + f2v;
        float s1 = wave_sum(v);
        if (!(tid & 63)) rwm[tid >> 6] = s1;
    }
    __syncthreads();
    float dv = 0.f;
    if (tid < 512) {
        float mu = (rwm[r*4] + rwm[r*4+1] + rwm[r*4+2] + rwm[r*4+3]) * (1.0f/256.0f);
        dv = v - mu;
        float s2 = wave_sum(dv * dv);
        if (!(tid & 63)) rws[tid >> 6] = s2;
    }
    __syncthreads();
    if (tid < 512) {
        float var = (rws[r*4] + rws[r*4+1] + rws[r*4+2] + rws[r*4+3]) * (1.0f/256.0f);
        hout[(i0 + r) * D + cc] = dv * rsqrtf(var + 1e-6f) * lng[cc] + lnb[cc];
    }
}

extern "C" void kernel_launch(void* const* d_in, const int* in_sizes, int n_in,
                              void* d_out, int out_size, void* d_ws, size_t ws_size,
                              hipStream_t stream)
{
    const int*   x       = (const int*)d_in[0];
    const float* mask    = (const float*)d_in[1];
    const int*   use_pos = (const int*)d_in[3];
    const float* pos_enc = (const float*)d_in[4];
    const float* emb_W   = (const float*)d_in[5];
    const float* emb_b   = (const float*)d_in[6];
    const float* nn_W1   = (const float*)d_in[7];
    const float* nn_b1   = (const float*)d_in[8];
    const float* nn_W2   = (const float*)d_in[9];
    const float* nn_b2   = (const float*)d_in[10];
    const float* w_W     = (const float*)d_in[11];
    const float* w_b     = (const float*)d_in[12];
    const float* out_W   = (const float*)d_in[13];
    const float* out_b   = (const float*)d_in[14];
    const float* ffn_W1  = (const float*)d_in[15];
    const float* ffn_b1  = (const float*)d_in[16];
    const float* ffn_W2  = (const float*)d_in[17];
    const float* ffn_b2  = (const float*)d_in[18];
    const float* ln1_g   = (const float*)d_in[19];
    const float* ln1_b   = (const float*)d_in[20];
    const float* ln2_g   = (const float*)d_in[21];
    const float* ln2_b   = (const float*)d_in[22];

    float* ws  = (float*)d_ws;
    float* h   = ws;
    float* qkv = ws + 131072;
    float* qa  = ws + 262144;
    float* qbT = ws + 393216;
    float* g   = ws + 524288;
    float* gT  = ws + 655360;
    float* o1  = ws + 786432;
    uint32* pw = (uint32*)(ws + 917504);   // 720896 dwords

    k0<<<1024, 256, 0, stream>>>(x, mask, use_pos, pos_enc, emb_W, emb_b,
                                 w_W, nn_W1, out_W, ffn_W1, ffn_W2, h, pw);

    for (int l = 0; l < 2; l++) {
        kA<<<256, 1024, 0, stream>>>(h, pw + l * 32768, pw + 65536, pw + 98304,
                                     w_b + l * D, nn_b1, qkv, qa, qbT);
        kB<<<dim3(64, 4), 1024, 0, stream>>>(qa, qbT, nn_W2, g, gT);
        kC<<<256, 1024, 0, stream>>>(g, gT, mask, nn_b2, qkv,
                                     pw + 131072 + l * 32768, out_b + l * D, h,
                                     ln1_g + l * D, ln1_b + l * D, o1);
        float* hout = (l == 1) ? (float*)d_out : h;
        kD<<<256, 1024, 0, stream>>>(o1, pw + 196608 + l * 131072,
                                     pw + 458752 + l * 131072,
                                     ffn_b1 + l * DFF, ffn_b2 + l * D,
                                     ln2_g + l * D, ln2_b + l * D, hout);
    }
}